// Round 12
// baseline (171.869 us; speedup 1.0000x reference)
//
#include <hip/hip_runtime.h>
#include <hip/hip_bf16.h>
#include <math.h>

#define N_NODES  50000
#define N_FEAT   128
#define DIM      10
#define N_EDGES  1600000
#define N_GRAPHS 1000
#define PSTRIDE  16   // padded row stride for p / q (64B-aligned rows)
#define CAP      80   // adjacency capacity per node; deg ~ Poisson(32), P(>80)~5e-13
#define BSH      8    // bucket = dst >> 8 (256 nodes per bucket)
#define NBUCK    196  // ceil(50000/256)
#define BCAP     9216 // per-bucket edge capacity; mean 8192, sd ~90 -> P(overflow)<1e-26
#define ACHUNK   2048 // edges per phase-A block (2048: 782 blocks -> ~3.8/CU occupancy)
#define ABLOCKS  ((N_EDGES + ACHUNK - 1) / ACHUNK)   // 782
#define PBLOCKS  ((N_NODES + 255) / 256)             // 196
#define SPLIT    8    // blocks per bucket in pull2B
#define GSLOTS   128  // LDS graph-partial slots (bucket spans ~6 graphs typically)

__device__ __forceinline__ float bf2f(unsigned short u) {
    union { unsigned int i; float f; } v;
    v.i = ((unsigned int)u) << 16;
    return v.f;
}

// generic float-array element load: fm=1 -> f32, fm=0 -> bf16
__device__ __forceinline__ float wload(const void* w, int fm, int i) {
    return fm ? ((const float*)w)[i] : bf2f(((const unsigned short*)w)[i]);
}

// generic int-array element load: im=1 -> int64, im=0 -> int32
__device__ __forceinline__ int iload(const void* p, int im, long long pos) {
    return im ? (int)((const long long*)p)[pos] : ((const int*)p)[pos];
}

// One block: detect dtypes, fold Wfc through W2 (vl/vr), zero bcur/gsum/gcnt.
__global__ void detect_setup_kernel(
    const unsigned short* __restrict__ w1l, const unsigned int* __restrict__ ei32,
    const void* __restrict__ W2l, const void* __restrict__ W2r,
    const void* __restrict__ Wfc,
    int* __restrict__ fmode, int* __restrict__ imode,
    float* __restrict__ vl, float* __restrict__ vr,
    int* __restrict__ bcur, float* __restrict__ gsum, float* __restrict__ gcnt) {
    __shared__ int bigcnt, oddnz;
    if (threadIdx.x == 0) { bigcnt = 0; oddnz = 0; }
    __syncthreads();
    // float dtype probe: bf16 view of W1_l (|w|<1); f32 low-halves have huge exponents
    for (int i = threadIdx.x; i < DIM * N_FEAT; i += 256) {
        int expo = (w1l[i] >> 7) & 0xFF;
        if (expo >= 0x90) atomicAdd(&bigcnt, 1);
    }
    // int dtype probe: int64 values < 2^31 have all-zero high words
    for (int i = threadIdx.x; i < 2048; i += 256) {
        if (ei32[2 * i + 1] != 0) atomicAdd(&oddnz, 1);
    }
    // zero the accumulator tables (replaces hipMemsetAsync dispatch)
    for (int i = threadIdx.x; i < NBUCK; i += 256) bcur[i] = 0;
    for (int i = threadIdx.x; i < N_GRAPHS; i += 256) { gsum[i] = 0.f; gcnt[i] = 0.f; }
    __syncthreads();
    int fm = (bigcnt >= 4) ? 1 : 0;
    if (threadIdx.x == 0) { *fmode = fm; *imode = (oddnz == 0) ? 1 : 0; }
    int j = threadIdx.x;
    if (j < DIM) {
        float al = 0.f, ar = 0.f;
        for (int i = 0; i < DIM; i++) {
            float w = wload(Wfc, fm, i);
            al += w * wload(W2l, fm, i * DIM + j);
            ar += w * wload(W2r, fm, i * DIM + j);
        }
        vl[j] = al;
        vr[j] = ar;
    } else if (j < 16) {
        vl[j] = 0.f;
        vr[j] = 0.f;
    }
}

#define ACCUM8(f0)                                                  \
    _Pragma("unroll")                                               \
    for (int d = 0; d < DIM; d++) {                                 \
        _Pragma("unroll")                                           \
        for (int k = 0; k < 8; k++) {                               \
            accl[d] += xf[k] * wl[d * N_FEAT + (f0) + k];           \
            accr[d] += xf[k] * wr[d * N_FEAT + (f0) + k];           \
        }                                                           \
    }

// Fused: blocks [0,ABLOCKS) bin edges into bucket segments (LDS bucket-sort ->
// coalesced runs); blocks [ABLOCKS, +PBLOCKS) compute p/q projections.
__global__ __launch_bounds__(256) void fusedA_kernel(
    const void* __restrict__ ei, const void* __restrict__ x,
    const void* __restrict__ W1l, const void* __restrict__ W1r,
    const int* __restrict__ fmode, const int* __restrict__ imode,
    int* __restrict__ bcur, unsigned int* __restrict__ bedges,
    float* __restrict__ p, float* __restrict__ q) {
    __shared__ union U {
        struct {
            unsigned int stage[ACHUNK];
            unsigned int sorted[ACHUNK];
            int hcnt[NBUCK]; int hbase[NBUCK]; int hpre[NBUCK];
        } a;                                                  // ~18.4 KB
        struct { float wl[DIM * N_FEAT]; float wr[DIM * N_FEAT]; } b;  // 10 KB
    } sh;

    if (blockIdx.x < ABLOCKS) {
        // ---- binning: record = src:16 | nidx:8 | bucket:8 ----
        int im = *imode;
        for (int b = threadIdx.x; b < NBUCK; b += 256) sh.a.hcnt[b] = 0;
        __syncthreads();
        long long e0 = (long long)blockIdx.x * ACHUNK;
        int nE = (int)min((long long)ACHUNK, (long long)N_EDGES - e0);
        for (int i = threadIdx.x; i < nE; i += 256) {
            int s = iload(ei, im, e0 + i);
            int d = iload(ei, im, (long long)N_EDGES + e0 + i);
            sh.a.stage[i] = (unsigned)s | ((unsigned)(d & 255) << 16) | ((unsigned)(d >> BSH) << 24);
            atomicAdd(&sh.a.hcnt[d >> BSH], 1);
        }
        __syncthreads();
        // exclusive prefix over buckets (serial, hidden by inter-block TLP)
        if (threadIdx.x == 0) {
            int run = 0;
            for (int b = 0; b < NBUCK; b++) { sh.a.hpre[b] = run; run += sh.a.hcnt[b]; }
        }
        __syncthreads();
        for (int b = threadIdx.x; b < NBUCK; b += 256) {
            int c = sh.a.hcnt[b];
            sh.a.hbase[b] = c ? atomicAdd(&bcur[b], c) : 0;
            sh.a.hcnt[b] = 0;   // reuse as local cursor
        }
        __syncthreads();
        // LDS bucket-sort
        for (int i = threadIdx.x; i < nE; i += 256) {
            unsigned rec = sh.a.stage[i];
            int b = rec >> 24;
            int pos = sh.a.hpre[b] + atomicAdd(&sh.a.hcnt[b], 1);
            sh.a.sorted[pos] = rec;
        }
        __syncthreads();
        // coalesced write-out: consecutive i within a bucket -> consecutive gpos
        for (int i = threadIdx.x; i < nE; i += 256) {
            unsigned rec = sh.a.sorted[i];
            int b = rec >> 24;
            int gpos = sh.a.hbase[b] + (i - sh.a.hpre[b]);
            if (gpos < BCAP) bedges[(size_t)b * BCAP + gpos] = rec;
        }
    } else {
        // ---- projection: p = W1_l @ x[n], q = W1_r @ x[n] ----
        int fm = *fmode;
        float* wl = sh.b.wl;
        float* wr = sh.b.wr;
        for (int i = threadIdx.x; i < DIM * N_FEAT; i += 256) {
            wl[i] = wload(W1l, fm, i);
            wr[i] = wload(W1r, fm, i);
        }
        __syncthreads();
        int n = (blockIdx.x - ABLOCKS) * 256 + threadIdx.x;
        if (n >= N_NODES) return;

        float accl[DIM], accr[DIM];
#pragma unroll
        for (int d = 0; d < DIM; d++) { accl[d] = 0.f; accr[d] = 0.f; }

        if (fm) {
            const float4* xr = reinterpret_cast<const float4*>((const float*)x + (size_t)n * N_FEAT);
            for (int fb = 0; fb < N_FEAT / 8; fb++) {
                float4 v0 = xr[2 * fb];
                float4 v1 = xr[2 * fb + 1];
                float xf[8] = {v0.x, v0.y, v0.z, v0.w, v1.x, v1.y, v1.z, v1.w};
                ACCUM8(fb * 8)
            }
        } else {
            const uint4* xr = reinterpret_cast<const uint4*>((const unsigned short*)x + (size_t)n * N_FEAT);
            for (int fb = 0; fb < N_FEAT / 8; fb++) {
                uint4 v = xr[fb];
                float xf[8];
                xf[0] = bf2f((unsigned short)(v.x & 0xffff)); xf[1] = bf2f((unsigned short)(v.x >> 16));
                xf[2] = bf2f((unsigned short)(v.y & 0xffff)); xf[3] = bf2f((unsigned short)(v.y >> 16));
                xf[4] = bf2f((unsigned short)(v.z & 0xffff)); xf[5] = bf2f((unsigned short)(v.z >> 16));
                xf[6] = bf2f((unsigned short)(v.w & 0xffff)); xf[7] = bf2f((unsigned short)(v.w >> 16));
                ACCUM8(fb * 8)
            }
        }
        float* pr = p + (size_t)n * PSTRIDE;
        float* qr = q + (size_t)n * PSTRIDE;
#pragma unroll
        for (int d = 0; d < DIM; d++) { pr[d] = accl[d]; qr[d] = accr[d]; }
#pragma unroll
        for (int d = DIM; d < PSTRIDE; d++) { pr[d] = 0.f; qr[d] = 0.f; }
    }
}

// Phase B: one block per bucket, 1024 threads; build cnt+col in LDS, write coalesced.
__global__ __launch_bounds__(1024) void binB_kernel(
    const int* __restrict__ bcur, const unsigned int* __restrict__ bedges,
    int* __restrict__ cnt, unsigned short* __restrict__ col) {
    __shared__ unsigned short lcol[256 * CAP];   // 40 KB
    __shared__ int lcnt[256];
    int b = blockIdx.x;
    if (threadIdx.x < 256) lcnt[threadIdx.x] = 0;
    __syncthreads();
    int m = min(bcur[b], BCAP);
    const unsigned int* seg = bedges + (size_t)b * BCAP;
    for (int i = threadIdx.x; i < m; i += 1024) {
        unsigned rec = seg[i];
        int nidx = (rec >> 16) & 255;
        int pos = atomicAdd(&lcnt[nidx], 1);
        if (pos < CAP) lcol[nidx * CAP + pos] = (unsigned short)(rec & 0xffffu);
    }
    __syncthreads();
    int node0 = b << BSH;
    int nvalid = min(256, N_NODES - node0);
    if ((int)threadIdx.x < nvalid) cnt[node0 + threadIdx.x] = lcnt[threadIdx.x];
    int total = nvalid * CAP / 8;   // CAP divisible by 8
    uint4* dst4 = (uint4*)(col + (size_t)node0 * CAP);
    const uint4* src4 = (const uint4*)lcol;
    for (int i = threadIdx.x; i < total; i += 1024) dst4[i] = src4[i];
}

// Pull pass 1 (fused SAGE layer1 + ReLU + fold to scalars t,u): 16 lanes/node.
// Neighbor indices batch-loaded as uint4 (8 per 16B, HW same-address broadcast).
__global__ __launch_bounds__(256) void pull1_kernel(
    const int* __restrict__ cnt, const unsigned short* __restrict__ col,
    const float* __restrict__ p, const float* __restrict__ q,
    const float* __restrict__ vl, const float* __restrict__ vr,
    float* __restrict__ t, float* __restrict__ u, float* __restrict__ dinv) {
    int g = blockIdx.x * 16 + (threadIdx.x >> 4);
    int sub = threadIdx.x & 15;
    if (g >= N_NODES) return;
    int deg = cnt[g];
    int dcl = min(deg, CAP);
    const unsigned short* cl = col + (size_t)g * CAP;   // 160B rows, 16B-aligned
    float acc = 0.f;
    for (int k0 = 0; k0 < dcl; k0 += 8) {
        uint4 cv = *reinterpret_cast<const uint4*>(cl + k0);
        int cs[8];
        cs[0] = cv.x & 0xffff; cs[1] = cv.x >> 16;
        cs[2] = cv.y & 0xffff; cs[3] = cv.y >> 16;
        cs[4] = cv.z & 0xffff; cs[5] = cv.z >> 16;
        cs[6] = cv.w & 0xffff; cs[7] = cv.w >> 16;
#pragma unroll
        for (int j = 0; j < 8; j++) {
            // always load (garbage index <=65535 stays inside mapped ws), mask the add
            float v = p[(size_t)cs[j] * PSTRIDE + sub];
            acc += (k0 + j < dcl) ? v : 0.f;
        }
    }
    float di = 1.0f / fmaxf((float)deg, 1.0f);
    float h = fmaxf(acc * di + q[(size_t)g * PSTRIDE + sub], 0.f);
    float tv = h * vl[sub];
    float uv = h * vr[sub];
#pragma unroll
    for (int off = 8; off > 0; off >>= 1) {
        tv += __shfl_xor(tv, off, 16);
        uv += __shfl_xor(uv, off, 16);
    }
    if (sub == 0) {
        t[g] = tv;
        u[g] = uv;
        dinv[g] = di;
    }
}

// Layer-2 + pooling from the bedges STREAM (no col re-read): SPLIT blocks per
// bucket; per-bucket dinv/batch in LDS; per-graph partials in LDS, ~rng global
// atomics per block. sum_n dinv[n]*sum_{src in N(n)} t[src] == sum_e t[src]*dinv[dst].
__global__ __launch_bounds__(256) void pull2B_kernel(
    const int* __restrict__ bcur, const unsigned int* __restrict__ bedges,
    const float* __restrict__ t, const float* __restrict__ u,
    const float* __restrict__ dinv, const void* __restrict__ batch,
    const int* __restrict__ imode,
    float* __restrict__ gsum, float* __restrict__ gcnt) {
    __shared__ float ldinv[256];
    __shared__ int   lb[256];
    __shared__ float lgs[GSLOTS];
    __shared__ float lgc[GSLOTS];
    int b = blockIdx.x / SPLIT;
    int s = blockIdx.x % SPLIT;
    int tid = threadIdx.x;
    int node0 = b << BSH;
    int nvalid = min(256, N_NODES - node0);
    int im = *imode;
    if (tid < nvalid) {
        ldinv[tid] = dinv[node0 + tid];
        lb[tid] = iload(batch, im, node0 + tid);
    }
    if (tid < GSLOTS) { lgs[tid] = 0.f; lgc[tid] = 0.f; }
    __syncthreads();
    int g0 = lb[0];
    int rng = lb[nvalid - 1] - g0 + 1;   // batch sorted -> contiguous graph range
    bool useLDS = (rng <= GSLOTS);
    int m = min(bcur[b], BCAP);
    int c0 = (m * s) / SPLIT, c1 = (m * (s + 1)) / SPLIT;
    const unsigned int* seg = bedges + (size_t)b * BCAP;
    for (int i = c0 + tid; i < c1; i += 256) {
        unsigned rec = seg[i];
        int src  = rec & 0xffffu;
        int nidx = (rec >> 16) & 255;
        float val = t[src] * ldinv[nidx];
        int gg = lb[nidx];
        if (useLDS) atomicAdd(&lgs[gg - g0], val);
        else        atomicAdd(gsum + gg, val);
    }
    // s==0 sub-block folds in the node terms: u[n] and the graph node-count
    if (s == 0 && tid < nvalid) {
        int gg = lb[tid];
        float uval = u[node0 + tid];
        if (useLDS) {
            atomicAdd(&lgs[gg - g0], uval);
            atomicAdd(&lgc[gg - g0], 1.0f);
        } else {
            atomicAdd(gsum + gg, uval);
            atomicAdd(gcnt + gg, 1.0f);
        }
    }
    __syncthreads();
    if (useLDS) {
        for (int i = tid; i < rng; i += 256) {
            float v = lgs[i];
            if (v != 0.f) atomicAdd(gsum + g0 + i, v);
            if (s == 0) {
                float c = lgc[i];
                if (c != 0.f) atomicAdd(gcnt + g0 + i, c);
            }
        }
    }
}

__global__ __launch_bounds__(256) void final_kernel(
    const float* __restrict__ gsum, const float* __restrict__ gcnt,
    const int* __restrict__ fmode, void* __restrict__ out) {
    int g = blockIdx.x * 256 + threadIdx.x;
    if (g >= N_GRAPHS) return;
    float pooled = gsum[g] / fmaxf(gcnt[g], 1.0f);
    float sg = 1.0f / (1.0f + expf(-pooled));
    if (*fmode) {
        ((float*)out)[g] = sg;
    } else {
        ((__hip_bfloat16*)out)[g] = __float2bfloat16(sg);
    }
}

extern "C" void kernel_launch(void* const* d_in, const int* in_sizes, int n_in,
                              void* d_out, int out_size, void* d_ws, size_t ws_size,
                              hipStream_t stream) {
    const void* x    = d_in[0];
    const void* W1l  = d_in[1];
    const void* W1r  = d_in[2];
    const void* W2l  = d_in[3];
    const void* W2r  = d_in[4];
    const void* Wfc  = d_in[5];
    const void* ei   = d_in[6];   // [2, E] flat: src then dst
    const void* batc = d_in[7];

    // ws is 256 MiB; ~22 MB used, no aliasing needed
    char* ws = (char*)d_ws;
    int*   fmode = (int*)ws;
    int*   imode = fmode + 1;
    float* vl   = (float*)(ws + 64);                      // 16
    float* vr   = vl + 16;                                // 16
    int*   bcur = (int*)(vr + 16);                        // NBUCK
    float* gsum = (float*)(bcur + NBUCK);                 // N_GRAPHS
    float* gcnt = gsum + N_GRAPHS;                        // N_GRAPHS
    unsigned int* bedges = (unsigned int*)(ws + ((((size_t)(gcnt + N_GRAPHS) - (size_t)ws) + 255) & ~(size_t)255));
    int*   cnt  = (int*)(bedges + (size_t)NBUCK * BCAP);     // N_NODES
    unsigned short* col = (unsigned short*)(cnt + N_NODES);  // N_NODES*CAP
    float* p    = (float*)(col + (size_t)N_NODES * CAP);     // N_NODES*PSTRIDE
    float* q    = p + (size_t)N_NODES * PSTRIDE;             // N_NODES*PSTRIDE
    float* t    = q + (size_t)N_NODES * PSTRIDE;             // N_NODES
    float* u    = t + N_NODES;                               // N_NODES
    float* dinv = u + N_NODES;                               // N_NODES

    detect_setup_kernel<<<1, 256, 0, stream>>>(
        (const unsigned short*)W1l, (const unsigned int*)ei, W2l, W2r, Wfc,
        fmode, imode, vl, vr, bcur, gsum, gcnt);
    fusedA_kernel<<<ABLOCKS + PBLOCKS, 256, 0, stream>>>(
        ei, x, W1l, W1r, fmode, imode, bcur, bedges, p, q);
    binB_kernel<<<NBUCK, 1024, 0, stream>>>(bcur, bedges, cnt, col);
    pull1_kernel<<<(N_NODES * 16 + 255) / 256, 256, 0, stream>>>(cnt, col, p, q, vl, vr, t, u, dinv);
    pull2B_kernel<<<NBUCK * SPLIT, 256, 0, stream>>>(bcur, bedges, t, u, dinv, batc, imode, gsum, gcnt);
    final_kernel<<<(N_GRAPHS + 255) / 256, 256, 0, stream>>>(gsum, gcnt, fmode, d_out);
}

// Round 13
// 165.181 us; speedup vs baseline: 1.0405x; 1.0405x over previous
//
#include <hip/hip_runtime.h>
#include <hip/hip_bf16.h>
#include <math.h>

#define N_NODES  50000
#define N_FEAT   128
#define DIM      10
#define N_EDGES  1600000
#define N_GRAPHS 1000
#define PSTRIDE  16   // padded row stride for p / q (64B-aligned rows)
#define CAP      80   // adjacency capacity per node; deg ~ Poisson(32), P(>80)~5e-13
#define BSH      8    // bucket = dst >> 8 (256 nodes per bucket)
#define NBUCK    196  // ceil(50000/256)
#define BCAP     9216 // per-bucket edge capacity; mean 8192, sd ~90 -> P(overflow)<1e-26
#define ACHUNK   4096 // edges per phase-A block
#define ABLOCKS  ((N_EDGES + ACHUNK - 1) / ACHUNK)   // 391
#define PBLOCKS  ((N_NODES + 255) / 256)             // 196
#define SPLIT    8    // blocks per bucket in pull2B
#define GSLOTS   128  // LDS graph-partial slots (bucket spans ~6 graphs typically)

__device__ __forceinline__ float bf2f(unsigned short u) {
    union { unsigned int i; float f; } v;
    v.i = ((unsigned int)u) << 16;
    return v.f;
}

// generic float-array element load: fm=1 -> f32, fm=0 -> bf16
__device__ __forceinline__ float wload(const void* w, int fm, int i) {
    return fm ? ((const float*)w)[i] : bf2f(((const unsigned short*)w)[i]);
}

// generic int-array element load: im=1 -> int64, im=0 -> int32
__device__ __forceinline__ int iload(const void* p, int im, long long pos) {
    return im ? (int)((const long long*)p)[pos] : ((const int*)p)[pos];
}

// One block: detect dtypes, fold Wfc through W2 (vl/vr), zero bcur/gsum/gcnt.
__global__ void detect_setup_kernel(
    const unsigned short* __restrict__ w1l, const unsigned int* __restrict__ ei32,
    const void* __restrict__ W2l, const void* __restrict__ W2r,
    const void* __restrict__ Wfc,
    int* __restrict__ fmode, int* __restrict__ imode,
    float* __restrict__ vl, float* __restrict__ vr,
    int* __restrict__ bcur, float* __restrict__ gsum, float* __restrict__ gcnt) {
    __shared__ int bigcnt, oddnz;
    if (threadIdx.x == 0) { bigcnt = 0; oddnz = 0; }
    __syncthreads();
    // float dtype probe: bf16 view of W1_l (|w|<1); f32 low-halves have huge exponents
    for (int i = threadIdx.x; i < DIM * N_FEAT; i += 256) {
        int expo = (w1l[i] >> 7) & 0xFF;
        if (expo >= 0x90) atomicAdd(&bigcnt, 1);
    }
    // int dtype probe: int64 values < 2^31 have all-zero high words
    for (int i = threadIdx.x; i < 2048; i += 256) {
        if (ei32[2 * i + 1] != 0) atomicAdd(&oddnz, 1);
    }
    // zero the accumulator tables (replaces hipMemsetAsync dispatch)
    for (int i = threadIdx.x; i < NBUCK; i += 256) bcur[i] = 0;
    for (int i = threadIdx.x; i < N_GRAPHS; i += 256) { gsum[i] = 0.f; gcnt[i] = 0.f; }
    __syncthreads();
    int fm = (bigcnt >= 4) ? 1 : 0;
    if (threadIdx.x == 0) { *fmode = fm; *imode = (oddnz == 0) ? 1 : 0; }
    int j = threadIdx.x;
    if (j < DIM) {
        float al = 0.f, ar = 0.f;
        for (int i = 0; i < DIM; i++) {
            float w = wload(Wfc, fm, i);
            al += w * wload(W2l, fm, i * DIM + j);
            ar += w * wload(W2r, fm, i * DIM + j);
        }
        vl[j] = al;
        vr[j] = ar;
    } else if (j < 16) {
        vl[j] = 0.f;
        vr[j] = 0.f;
    }
}

#define ACCUM8(f0)                                                  \
    _Pragma("unroll")                                               \
    for (int d = 0; d < DIM; d++) {                                 \
        _Pragma("unroll")                                           \
        for (int k = 0; k < 8; k++) {                               \
            accl[d] += xf[k] * wl[d * N_FEAT + (f0) + k];           \
            accr[d] += xf[k] * wr[d * N_FEAT + (f0) + k];           \
        }                                                           \
    }

// Fused: blocks [0,ABLOCKS) bin edges into bucket segments; blocks [ABLOCKS, +PBLOCKS)
// compute p/q projections. Independent HBM streams (ei vs x) overlap.
__global__ __launch_bounds__(256) void fusedA_kernel(
    const void* __restrict__ ei, const void* __restrict__ x,
    const void* __restrict__ W1l, const void* __restrict__ W1r,
    const int* __restrict__ fmode, const int* __restrict__ imode,
    int* __restrict__ bcur, unsigned int* __restrict__ bedges,
    float* __restrict__ p, float* __restrict__ q) {
    __shared__ union U {
        struct { unsigned int stage[ACHUNK]; int hcnt[NBUCK]; int hbase[NBUCK]; } a;
        struct { float wl[DIM * N_FEAT]; float wr[DIM * N_FEAT]; } b;
    } sh;

    if (blockIdx.x < ABLOCKS) {
        // ---- binning: record = src:16 | nidx:8 | bucket:8 ----
        int im = *imode;
        for (int b = threadIdx.x; b < NBUCK; b += 256) sh.a.hcnt[b] = 0;
        __syncthreads();
        long long e0 = (long long)blockIdx.x * ACHUNK;
        int nE = (int)min((long long)ACHUNK, (long long)N_EDGES - e0);
        for (int i = threadIdx.x; i < nE; i += 256) {
            int s = iload(ei, im, e0 + i);
            int d = iload(ei, im, (long long)N_EDGES + e0 + i);
            sh.a.stage[i] = (unsigned)s | ((unsigned)(d & 255) << 16) | ((unsigned)(d >> BSH) << 24);
            atomicAdd(&sh.a.hcnt[d >> BSH], 1);
        }
        __syncthreads();
        for (int b = threadIdx.x; b < NBUCK; b += 256) {
            int c = sh.a.hcnt[b];
            sh.a.hbase[b] = c ? atomicAdd(&bcur[b], c) : 0;
            sh.a.hcnt[b] = 0;   // reuse as local cursor
        }
        __syncthreads();
        for (int i = threadIdx.x; i < nE; i += 256) {
            unsigned rec = sh.a.stage[i];
            int b = rec >> 24;
            int pos = sh.a.hbase[b] + atomicAdd(&sh.a.hcnt[b], 1);
            if (pos < BCAP) bedges[(size_t)b * BCAP + pos] = rec;
        }
    } else {
        // ---- projection: p = W1_l @ x[n], q = W1_r @ x[n] ----
        int fm = *fmode;
        float* wl = sh.b.wl;
        float* wr = sh.b.wr;
        for (int i = threadIdx.x; i < DIM * N_FEAT; i += 256) {
            wl[i] = wload(W1l, fm, i);
            wr[i] = wload(W1r, fm, i);
        }
        __syncthreads();
        int n = (blockIdx.x - ABLOCKS) * 256 + threadIdx.x;
        if (n >= N_NODES) return;

        float accl[DIM], accr[DIM];
#pragma unroll
        for (int d = 0; d < DIM; d++) { accl[d] = 0.f; accr[d] = 0.f; }

        if (fm) {
            const float4* xr = reinterpret_cast<const float4*>((const float*)x + (size_t)n * N_FEAT);
            for (int fb = 0; fb < N_FEAT / 8; fb++) {
                float4 v0 = xr[2 * fb];
                float4 v1 = xr[2 * fb + 1];
                float xf[8] = {v0.x, v0.y, v0.z, v0.w, v1.x, v1.y, v1.z, v1.w};
                ACCUM8(fb * 8)
            }
        } else {
            const uint4* xr = reinterpret_cast<const uint4*>((const unsigned short*)x + (size_t)n * N_FEAT);
            for (int fb = 0; fb < N_FEAT / 8; fb++) {
                uint4 v = xr[fb];
                float xf[8];
                xf[0] = bf2f((unsigned short)(v.x & 0xffff)); xf[1] = bf2f((unsigned short)(v.x >> 16));
                xf[2] = bf2f((unsigned short)(v.y & 0xffff)); xf[3] = bf2f((unsigned short)(v.y >> 16));
                xf[4] = bf2f((unsigned short)(v.z & 0xffff)); xf[5] = bf2f((unsigned short)(v.z >> 16));
                xf[6] = bf2f((unsigned short)(v.w & 0xffff)); xf[7] = bf2f((unsigned short)(v.w >> 16));
                ACCUM8(fb * 8)
            }
        }
        float* pr = p + (size_t)n * PSTRIDE;
        float* qr = q + (size_t)n * PSTRIDE;
#pragma unroll
        for (int d = 0; d < DIM; d++) { pr[d] = accl[d]; qr[d] = accr[d]; }
#pragma unroll
        for (int d = DIM; d < PSTRIDE; d++) { pr[d] = 0.f; qr[d] = 0.f; }
    }
}

// Phase B: one block per bucket, 1024 threads; build cnt+col in LDS, write coalesced.
__global__ __launch_bounds__(1024) void binB_kernel(
    const int* __restrict__ bcur, const unsigned int* __restrict__ bedges,
    int* __restrict__ cnt, unsigned short* __restrict__ col) {
    __shared__ unsigned short lcol[256 * CAP];   // 40 KB
    __shared__ int lcnt[256];
    int b = blockIdx.x;
    if (threadIdx.x < 256) lcnt[threadIdx.x] = 0;
    __syncthreads();
    int m = min(bcur[b], BCAP);
    const unsigned int* seg = bedges + (size_t)b * BCAP;
    for (int i = threadIdx.x; i < m; i += 1024) {
        unsigned rec = seg[i];
        int nidx = (rec >> 16) & 255;
        int pos = atomicAdd(&lcnt[nidx], 1);
        if (pos < CAP) lcol[nidx * CAP + pos] = (unsigned short)(rec & 0xffffu);
    }
    __syncthreads();
    int node0 = b << BSH;
    int nvalid = min(256, N_NODES - node0);
    if ((int)threadIdx.x < nvalid) cnt[node0 + threadIdx.x] = lcnt[threadIdx.x];
    int total = nvalid * CAP / 8;   // CAP divisible by 8
    uint4* dst4 = (uint4*)(col + (size_t)node0 * CAP);
    const uint4* src4 = (const uint4*)lcol;
    for (int i = threadIdx.x; i < total; i += 1024) dst4[i] = src4[i];
}

// Pull pass 1 (fused SAGE layer1 + ReLU + fold to scalars t,u): 16 lanes/node.
// Neighbor indices batch-loaded as uint4 (8 per 16B, HW same-address broadcast).
__global__ __launch_bounds__(256) void pull1_kernel(
    const int* __restrict__ cnt, const unsigned short* __restrict__ col,
    const float* __restrict__ p, const float* __restrict__ q,
    const float* __restrict__ vl, const float* __restrict__ vr,
    float* __restrict__ t, float* __restrict__ u, float* __restrict__ dinv) {
    int g = blockIdx.x * 16 + (threadIdx.x >> 4);
    int sub = threadIdx.x & 15;
    if (g >= N_NODES) return;
    int deg = cnt[g];
    int dcl = min(deg, CAP);
    const unsigned short* cl = col + (size_t)g * CAP;   // 160B rows, 16B-aligned
    float acc = 0.f;
    for (int k0 = 0; k0 < dcl; k0 += 8) {
        uint4 cv = *reinterpret_cast<const uint4*>(cl + k0);
        int cs[8];
        cs[0] = cv.x & 0xffff; cs[1] = cv.x >> 16;
        cs[2] = cv.y & 0xffff; cs[3] = cv.y >> 16;
        cs[4] = cv.z & 0xffff; cs[5] = cv.z >> 16;
        cs[6] = cv.w & 0xffff; cs[7] = cv.w >> 16;
#pragma unroll
        for (int j = 0; j < 8; j++) {
            // always load (garbage index <=65535 stays inside mapped ws), mask the add
            float v = p[(size_t)cs[j] * PSTRIDE + sub];
            acc += (k0 + j < dcl) ? v : 0.f;
        }
    }
    float di = 1.0f / fmaxf((float)deg, 1.0f);
    float h = fmaxf(acc * di + q[(size_t)g * PSTRIDE + sub], 0.f);
    float tv = h * vl[sub];
    float uv = h * vr[sub];
#pragma unroll
    for (int off = 8; off > 0; off >>= 1) {
        tv += __shfl_xor(tv, off, 16);
        uv += __shfl_xor(uv, off, 16);
    }
    if (sub == 0) {
        t[g] = tv;
        u[g] = uv;
        dinv[g] = di;
    }
}

// Layer-2 + pooling from the bedges STREAM (no col re-read): SPLIT blocks per
// bucket; per-bucket dinv/batch in LDS; per-graph partials in LDS, ~rng global
// atomics per block. sum_n dinv[n]*sum_{src in N(n)} t[src] == sum_e t[src]*dinv[dst].
__global__ __launch_bounds__(256) void pull2B_kernel(
    const int* __restrict__ bcur, const unsigned int* __restrict__ bedges,
    const float* __restrict__ t, const float* __restrict__ u,
    const float* __restrict__ dinv, const void* __restrict__ batch,
    const int* __restrict__ imode,
    float* __restrict__ gsum, float* __restrict__ gcnt) {
    __shared__ float ldinv[256];
    __shared__ int   lb[256];
    __shared__ float lgs[GSLOTS];
    __shared__ float lgc[GSLOTS];
    int b = blockIdx.x / SPLIT;
    int s = blockIdx.x % SPLIT;
    int tid = threadIdx.x;
    int node0 = b << BSH;
    int nvalid = min(256, N_NODES - node0);
    int im = *imode;
    if (tid < nvalid) {
        ldinv[tid] = dinv[node0 + tid];
        lb[tid] = iload(batch, im, node0 + tid);
    }
    if (tid < GSLOTS) { lgs[tid] = 0.f; lgc[tid] = 0.f; }
    __syncthreads();
    int g0 = lb[0];
    int rng = lb[nvalid - 1] - g0 + 1;   // batch sorted -> contiguous graph range
    bool useLDS = (rng <= GSLOTS);
    int m = min(bcur[b], BCAP);
    int c0 = (m * s) / SPLIT, c1 = (m * (s + 1)) / SPLIT;
    const unsigned int* seg = bedges + (size_t)b * BCAP;
    for (int i = c0 + tid; i < c1; i += 256) {
        unsigned rec = seg[i];
        int src  = rec & 0xffffu;
        int nidx = (rec >> 16) & 255;
        float val = t[src] * ldinv[nidx];
        int gg = lb[nidx];
        if (useLDS) atomicAdd(&lgs[gg - g0], val);
        else        atomicAdd(gsum + gg, val);
    }
    // s==0 sub-block folds in the node terms: u[n] and the graph node-count
    if (s == 0 && tid < nvalid) {
        int gg = lb[tid];
        float uval = u[node0 + tid];
        if (useLDS) {
            atomicAdd(&lgs[gg - g0], uval);
            atomicAdd(&lgc[gg - g0], 1.0f);
        } else {
            atomicAdd(gsum + gg, uval);
            atomicAdd(gcnt + gg, 1.0f);
        }
    }
    __syncthreads();
    if (useLDS) {
        for (int i = tid; i < rng; i += 256) {
            float v = lgs[i];
            if (v != 0.f) atomicAdd(gsum + g0 + i, v);
            if (s == 0) {
                float c = lgc[i];
                if (c != 0.f) atomicAdd(gcnt + g0 + i, c);
            }
        }
    }
}

__global__ __launch_bounds__(256) void final_kernel(
    const float* __restrict__ gsum, const float* __restrict__ gcnt,
    const int* __restrict__ fmode, void* __restrict__ out) {
    int g = blockIdx.x * 256 + threadIdx.x;
    if (g >= N_GRAPHS) return;
    float pooled = gsum[g] / fmaxf(gcnt[g], 1.0f);
    float sg = 1.0f / (1.0f + expf(-pooled));
    if (*fmode) {
        ((float*)out)[g] = sg;
    } else {
        ((__hip_bfloat16*)out)[g] = __float2bfloat16(sg);
    }
}

extern "C" void kernel_launch(void* const* d_in, const int* in_sizes, int n_in,
                              void* d_out, int out_size, void* d_ws, size_t ws_size,
                              hipStream_t stream) {
    const void* x    = d_in[0];
    const void* W1l  = d_in[1];
    const void* W1r  = d_in[2];
    const void* W2l  = d_in[3];
    const void* W2r  = d_in[4];
    const void* Wfc  = d_in[5];
    const void* ei   = d_in[6];   // [2, E] flat: src then dst
    const void* batc = d_in[7];

    // ws is 256 MiB; ~22 MB used, no aliasing needed
    char* ws = (char*)d_ws;
    int*   fmode = (int*)ws;
    int*   imode = fmode + 1;
    float* vl   = (float*)(ws + 64);                      // 16
    float* vr   = vl + 16;                                // 16
    int*   bcur = (int*)(vr + 16);                        // NBUCK
    float* gsum = (float*)(bcur + NBUCK);                 // N_GRAPHS
    float* gcnt = gsum + N_GRAPHS;                        // N_GRAPHS
    unsigned int* bedges = (unsigned int*)(ws + ((((size_t)(gcnt + N_GRAPHS) - (size_t)ws) + 255) & ~(size_t)255));
    int*   cnt  = (int*)(bedges + (size_t)NBUCK * BCAP);     // N_NODES
    unsigned short* col = (unsigned short*)(cnt + N_NODES);  // N_NODES*CAP
    float* p    = (float*)(col + (size_t)N_NODES * CAP);     // N_NODES*PSTRIDE
    float* q    = p + (size_t)N_NODES * PSTRIDE;             // N_NODES*PSTRIDE
    float* t    = q + (size_t)N_NODES * PSTRIDE;             // N_NODES
    float* u    = t + N_NODES;                               // N_NODES
    float* dinv = u + N_NODES;                               // N_NODES

    detect_setup_kernel<<<1, 256, 0, stream>>>(
        (const unsigned short*)W1l, (const unsigned int*)ei, W2l, W2r, Wfc,
        fmode, imode, vl, vr, bcur, gsum, gcnt);
    fusedA_kernel<<<ABLOCKS + PBLOCKS, 256, 0, stream>>>(
        ei, x, W1l, W1r, fmode, imode, bcur, bedges, p, q);
    binB_kernel<<<NBUCK, 1024, 0, stream>>>(bcur, bedges, cnt, col);
    pull1_kernel<<<(N_NODES * 16 + 255) / 256, 256, 0, stream>>>(cnt, col, p, q, vl, vr, t, u, dinv);
    pull2B_kernel<<<NBUCK * SPLIT, 256, 0, stream>>>(bcur, bedges, t, u, dinv, batc, imode, gsum, gcnt);
    final_kernel<<<(N_GRAPHS + 255) / 256, 256, 0, stream>>>(gsum, gcnt, fmode, d_out);
}